// Round 3
// baseline (178.646 us; speedup 1.0000x reference)
//
#include <hip/hip_runtime.h>
#include <hip/hip_bf16.h>

// BERT self-attention, B=8 S=1024 D=768 H=12 DH=64, fp32 in/out.
// (1) bf16 MFMA projection GEMM -> mixed (bf16, ws)
// (2) flash-style fused attention, QB=64 (high occupancy), async-stage
//     prefetch (T14), swizzled LDS, exp2 softmax, setprio on MFMA.

#define D_MODEL 768
#define SEQ     1024
#define NHEAD   12
#define DHEAD   64
#define BATCH   8
#define QB      64
#define LOG2E   1.44269504088896f

typedef __attribute__((ext_vector_type(8))) short bf16x8;
typedef __attribute__((ext_vector_type(4))) short bf16x4v;
typedef __attribute__((ext_vector_type(4))) float f32x4;

__device__ __forceinline__ unsigned short f2bf(float f) {
  __hip_bfloat16 h = __float2bfloat16(f);
  return *reinterpret_cast<unsigned short*>(&h);
}

__device__ __forceinline__ float fexp2(float x) {
#if __has_builtin(__builtin_amdgcn_exp2f)
  return __builtin_amdgcn_exp2f(x);
#else
  return exp2f(x);
#endif
}

// row-major [r][c] tile, 64 elems/row, 16B granules rotated by row
__device__ __forceinline__ int swz(int r, int c) {
  return (r << 6) + ((((c >> 3) + r) & 7) << 3) + (c & 7);
}
// transposed tile XT[d][t], granules rotated by d>>3
__device__ __forceinline__ int swzT(int d, int t) {
  return (d << 6) + ((((t >> 3) + (d >> 3)) & 7) << 3) + (t & 7);
}

// ---------------------------------------------------------------------------
// Projection GEMM: mixed = bf16(X @ W^T + b).  M=8192 N=768 K=768.
// ---------------------------------------------------------------------------
__global__ __launch_bounds__(256) void proj_kernel(
    const float* __restrict__ X, const float* __restrict__ W,
    const float* __restrict__ bias, unsigned short* __restrict__ mixed)
{
  __shared__ unsigned short As[128][40];
  __shared__ unsigned short Bs[128][40];

  const int tid = threadIdx.x;
  const int l   = tid & 63;
  const int w   = tid >> 6;
  const int m0  = blockIdx.x * 128;
  const int n0  = blockIdx.y * 128;
  const int wm  = (w >> 1) * 64;
  const int wn  = (w & 1) * 64;
  const int lr  = l & 15;
  const int lk  = (l >> 4) * 8;

  f32x4 acc[4][4] = {};

  for (int k0 = 0; k0 < D_MODEL; k0 += 32) {
    #pragma unroll
    for (int rr = 0; rr < 4; ++rr) {
      int p   = tid + rr * 256;
      int row = p >> 3;
      int cg  = (p & 7) * 4;
      f32x4 a  = *(const f32x4*)&X[(size_t)(m0 + row) * D_MODEL + k0 + cg];
      f32x4 bv = *(const f32x4*)&W[(size_t)(n0 + row) * D_MODEL + k0 + cg];
      bf16x4v ap, bp;
      #pragma unroll
      for (int j = 0; j < 4; ++j) { ap[j] = (short)f2bf(a[j]); bp[j] = (short)f2bf(bv[j]); }
      *(bf16x4v*)&As[row][cg] = ap;
      *(bf16x4v*)&Bs[row][cg] = bp;
    }
    __syncthreads();

    bf16x8 af[4], bfr[4];
    #pragma unroll
    for (int am = 0; am < 4; ++am) af[am]  = *(const bf16x8*)&As[wm + am * 16 + lr][lk];
    #pragma unroll
    for (int bn = 0; bn < 4; ++bn) bfr[bn] = *(const bf16x8*)&Bs[wn + bn * 16 + lr][lk];

    #pragma unroll
    for (int am = 0; am < 4; ++am)
      #pragma unroll
      for (int bn = 0; bn < 4; ++bn)
        acc[am][bn] = __builtin_amdgcn_mfma_f32_16x16x32_bf16(
            af[am], bfr[bn], acc[am][bn], 0, 0, 0);
    __syncthreads();
  }

  const int orow = (l >> 4) * 4;
  #pragma unroll
  for (int bn = 0; bn < 4; ++bn) {
    int   col  = n0 + wn + bn * 16 + lr;
    float bcol = bias[col];
    #pragma unroll
    for (int am = 0; am < 4; ++am)
      #pragma unroll
      for (int i = 0; i < 4; ++i) {
        int row = m0 + wm + am * 16 + orow + i;
        mixed[(size_t)row * D_MODEL + col] = f2bf(acc[am][bn][i] + bcol);
      }
  }
}

// ---------------------------------------------------------------------------
// Fused attention: 64 q-rows/block, 4 waves x 16 rows, async prefetch.
// ---------------------------------------------------------------------------
__global__ __launch_bounds__(256, 5) void attn_kernel(
    const unsigned short* __restrict__ mixed, const float* __restrict__ mask,
    float* __restrict__ out)
{
  __shared__ unsigned short Qs[QB * DHEAD];       // 8 KB
  __shared__ unsigned short Xs[64 * DHEAD];       // 8 KB
  __shared__ unsigned short XTs[DHEAD * 64];      // 8 KB
  __shared__ unsigned short Ps[4][16 * DHEAD];    // 8 KB (per wave)

  const int tid = threadIdx.x;
  const int l   = tid & 63;
  const int w   = tid >> 6;
  const int q0  = blockIdx.x * QB;
  const int h   = blockIdx.y;
  const int b   = blockIdx.z;
  const int lr  = l & 15;
  const int g   = l >> 4;
  const int lk  = g * 8;
  const size_t base = ((size_t)b * SEQ) * D_MODEL + h * DHEAD;

  // staging coords (shared by Q and X tiles): 64x64 in 2 passes
  const int srow0 = tid >> 3;            // pass 0 row
  const int scol  = (tid & 7) * 8;
  const int c8    = scol >> 3;

  // ---- stage Q (64 x 64) ----
  #pragma unroll
  for (int rr = 0; rr < 2; ++rr) {
    int row = srow0 + rr * 32;
    bf16x8 v = *(const bf16x8*)&mixed[base + (size_t)(q0 + row) * D_MODEL + scol];
    *(bf16x8*)&Qs[swz(row, scol)] = v;
  }

  // ---- prefetch X tile 0 into regs ----
  bf16x8 xr[2];
  #pragma unroll
  for (int rr = 0; rr < 2; ++rr)
    xr[rr] = *(const bf16x8*)&mixed[base + (size_t)(srow0 + rr * 32) * D_MODEL + scol];

  __syncthreads();
  bf16x8 qf[2];
  qf[0] = *(const bf16x8*)&Qs[swz(w * 16 + lr, lk)];
  qf[1] = *(const bf16x8*)&Qs[swz(w * 16 + lr, 32 + lk)];

  float m_i[4], l_i[4];
  f32x4 cacc[4] = {};
  #pragma unroll
  for (int i = 0; i < 4; ++i) { m_i[i] = -1e30f; l_i[i] = 0.f; }

  const float SCL = 0.125f * LOG2E;

  for (int t0 = 0; t0 < SEQ; t0 += 64) {
    // ---- write prefetched regs -> Xs + transposed XTs ----
    #pragma unroll
    for (int rr = 0; rr < 2; ++rr) {
      int row = srow0 + rr * 32;
      bf16x8 v = xr[rr];
      *(bf16x8*)&Xs[swz(row, scol)] = v;
      int xb = (scol << 6) + ((((row >> 3) + c8) & 7) << 3) + (row & 7);
      #pragma unroll
      for (int j = 0; j < 8; ++j)
        XTs[xb + (j << 6)] = (unsigned short)v[j];   // compile-time extract
    }
    __syncthreads();

    // ---- issue prefetch of next tile (consumed next iteration) ----
    if (t0 + 64 < SEQ) {
      #pragma unroll
      for (int rr = 0; rr < 2; ++rr)
        xr[rr] = *(const bf16x8*)&mixed[base +
                   (size_t)(t0 + 64 + srow0 + rr * 32) * D_MODEL + scol];
    }

    // ---- mask loads (issued early, used post-MFMA) ----
    float mk[4];
    #pragma unroll
    for (int nf = 0; nf < 4; ++nf)
      mk[nf] = mask[(size_t)b * SEQ + t0 + nf * 16 + lr] * LOG2E;

    // ---- S = Q @ X^T ----
    f32x4 sacc[4] = {};
    __builtin_amdgcn_s_setprio(1);
    #pragma unroll
    for (int kf = 0; kf < 2; ++kf)
      #pragma unroll
      for (int nf = 0; nf < 4; ++nf) {
        bf16x8 kfr = *(const bf16x8*)&Xs[swz(nf * 16 + lr, kf * 32 + lk)];
        sacc[nf] = __builtin_amdgcn_mfma_f32_16x16x32_bf16(
            qf[kf], kfr, sacc[nf], 0, 0, 0);
      }
    __builtin_amdgcn_s_setprio(0);

    // ---- scale + mask (exp2 domain), online softmax ----
    #pragma unroll
    for (int nf = 0; nf < 4; ++nf)
      #pragma unroll
      for (int i = 0; i < 4; ++i)
        sacc[nf][i] = sacc[nf][i] * SCL + mk[nf];

    #pragma unroll
    for (int i = 0; i < 4; ++i) {
      float rm = fmaxf(fmaxf(sacc[0][i], sacc[1][i]),
                       fmaxf(sacc[2][i], sacc[3][i]));
      rm = fmaxf(rm, __shfl_xor(rm, 1));
      rm = fmaxf(rm, __shfl_xor(rm, 2));
      rm = fmaxf(rm, __shfl_xor(rm, 4));
      rm = fmaxf(rm, __shfl_xor(rm, 8));
      float mn = fmaxf(m_i[i], rm);
      float al = fexp2(m_i[i] - mn);
      float rs = 0.f;
      #pragma unroll
      for (int nf = 0; nf < 4; ++nf) {
        float pv = fexp2(sacc[nf][i] - mn);
        sacc[nf][i] = pv;
        rs += pv;
      }
      rs += __shfl_xor(rs, 1);
      rs += __shfl_xor(rs, 2);
      rs += __shfl_xor(rs, 4);
      rs += __shfl_xor(rs, 8);
      l_i[i] = l_i[i] * al + rs;
      m_i[i] = mn;
      #pragma unroll
      for (int nf = 0; nf < 4; ++nf) cacc[nf][i] *= al;
    }

    // ---- P -> per-wave LDS (wave-private, no barrier) ----
    const int pr = g * 4;
    #pragma unroll
    for (int nf = 0; nf < 4; ++nf)
      #pragma unroll
      for (int i = 0; i < 4; ++i)
        Ps[w][swz(pr + i, nf * 16 + lr)] = f2bf(sacc[nf][i]);

    // ---- ctx += P @ X ----
    bf16x8 pa[2];
    pa[0] = *(const bf16x8*)&Ps[w][swz(lr, lk)];
    pa[1] = *(const bf16x8*)&Ps[w][swz(lr, 32 + lk)];
    __builtin_amdgcn_s_setprio(1);
    #pragma unroll
    for (int kf = 0; kf < 2; ++kf)
      #pragma unroll
      for (int nf = 0; nf < 4; ++nf) {
        bf16x8 vf = *(const bf16x8*)&XTs[swzT(nf * 16 + lr, kf * 32 + lk)];
        cacc[nf] = __builtin_amdgcn_mfma_f32_16x16x32_bf16(
            pa[kf], vf, cacc[nf], 0, 0, 0);
      }
    __builtin_amdgcn_s_setprio(0);
    __syncthreads();  // all reads of Xs/XTs done before next iter's writes
  }

  // ---- normalize + store ----
  #pragma unroll
  for (int i = 0; i < 4; ++i) {
    float inv = __builtin_amdgcn_rcpf(l_i[i]);
    #pragma unroll
    for (int nf = 0; nf < 4; ++nf) {
      int row = q0 + w * 16 + g * 4 + i;
      int col = h * DHEAD + nf * 16 + lr;
      out[((size_t)b * SEQ + row) * D_MODEL + col] = cacc[nf][i] * inv;
    }
  }
}

// ---------------------------------------------------------------------------
extern "C" void kernel_launch(void* const* d_in, const int* in_sizes, int n_in,
                              void* d_out, int out_size, void* d_ws, size_t ws_size,
                              hipStream_t stream) {
  const float* x    = (const float*)d_in[0];
  const float* mask = (const float*)d_in[1];
  const float* W    = (const float*)d_in[2];
  const float* bias = (const float*)d_in[3];
  float* out        = (float*)d_out;

  unsigned short* mixed = (unsigned short*)d_ws;  // [8192][768] bf16 = 12.6 MB

  dim3 gp(8192 / 128, D_MODEL / 128);             // (64, 6)
  proj_kernel<<<gp, 256, 0, stream>>>(x, W, bias, mixed);

  dim3 ga(SEQ / QB, NHEAD, BATCH);                // (16, 12, 8)
  attn_kernel<<<ga, 256, 0, stream>>>(mixed, mask, out);
}

// Round 4
// 116.960 us; speedup vs baseline: 1.5274x; 1.5274x over previous
//
#include <hip/hip_runtime.h>
#include <hip/hip_bf16.h>

// BERT self-attention, B=8 S=1024 D=768 H=12 DH=64, fp32 in/out.
// (1) bf16 MFMA projection GEMM -> mixed (row-major) AND mixedT (per-head
//     transposed [b][h][d][t]) in one pass.
// (2) flash-style fused attention: QB=64, 4 waves x 16 q-rows; K tile and
//     pre-transposed V tile both staged with coalesced b128 loads into
//     XOR-swizzled LDS; in-wave online softmax (exp2 domain); Q/P LDS alias.

#define D_MODEL 768
#define SEQ     1024
#define NHEAD   12
#define DHEAD   64
#define BATCH   8
#define QB      64
#define LOG2E   1.44269504088896f

typedef __attribute__((ext_vector_type(8))) short bf16x8;
typedef __attribute__((ext_vector_type(4))) short short4v;
typedef __attribute__((ext_vector_type(4))) float f32x4;

__device__ __forceinline__ unsigned short f2bf(float f) {
  __hip_bfloat16 h = __float2bfloat16(f);
  return *reinterpret_cast<unsigned short*>(&h);
}

__device__ __forceinline__ float fexp2(float x) {
#if __has_builtin(__builtin_amdgcn_exp2f)
  return __builtin_amdgcn_exp2f(x);
#else
  return exp2f(x);
#endif
}

// [64]-elem-wide bf16 tile, XOR granule swizzle (G4 recipe): elem index.
// Keeps 8-elem (16B) granules contiguous; reads/writes both apply it.
__device__ __forceinline__ int lswz(int r, int c) {
  return (r << 6) + (c ^ ((r & 7) << 3));
}

// ---------------------------------------------------------------------------
// Projection GEMM: mixed = bf16(X @ W^T + b); optionally also mixedT.
// M=8192 N=768 K=768.  BM=BN=128 BK=32, 4 waves 2x2, 64x64 each.
// ---------------------------------------------------------------------------
template<bool WRITE_T>
__global__ __launch_bounds__(256) void proj_kernel(
    const float* __restrict__ X, const float* __restrict__ W,
    const float* __restrict__ bias, unsigned short* __restrict__ mixed,
    unsigned short* __restrict__ mixedT)
{
  __shared__ unsigned short As[128][40];
  __shared__ unsigned short Bs[128][40];

  const int tid = threadIdx.x;
  const int l   = tid & 63;
  const int w   = tid >> 6;
  const int m0  = blockIdx.x * 128;
  const int n0  = blockIdx.y * 128;
  const int wm  = (w >> 1) * 64;
  const int wn  = (w & 1) * 64;
  const int lr  = l & 15;
  const int g   = l >> 4;
  const int lk  = g * 8;

  f32x4 acc[4][4] = {};

  for (int k0 = 0; k0 < D_MODEL; k0 += 32) {
    #pragma unroll
    for (int rr = 0; rr < 4; ++rr) {
      int p   = tid + rr * 256;
      int row = p >> 3;
      int cg  = (p & 7) * 4;
      f32x4 a  = *(const f32x4*)&X[(size_t)(m0 + row) * D_MODEL + k0 + cg];
      f32x4 bv = *(const f32x4*)&W[(size_t)(n0 + row) * D_MODEL + k0 + cg];
      short4v ap, bp;
      #pragma unroll
      for (int j = 0; j < 4; ++j) { ap[j] = (short)f2bf(a[j]); bp[j] = (short)f2bf(bv[j]); }
      *(short4v*)&As[row][cg] = ap;
      *(short4v*)&Bs[row][cg] = bp;
    }
    __syncthreads();

    bf16x8 af[4], bfr[4];
    #pragma unroll
    for (int am = 0; am < 4; ++am) af[am]  = *(const bf16x8*)&As[wm + am * 16 + lr][lk];
    #pragma unroll
    for (int bn = 0; bn < 4; ++bn) bfr[bn] = *(const bf16x8*)&Bs[wn + bn * 16 + lr][lk];

    #pragma unroll
    for (int am = 0; am < 4; ++am)
      #pragma unroll
      for (int bn = 0; bn < 4; ++bn)
        acc[am][bn] = __builtin_amdgcn_mfma_f32_16x16x32_bf16(
            af[am], bfr[bn], acc[am][bn], 0, 0, 0);
    __syncthreads();
  }

  // epilogue: C/D layout col = lane&15, row = g*4 + i
  const int orow = g * 4;
  const int bT   = m0 >> 10;                 // batch index (block within one b)
  const int tl0  = (m0 & 1023) + wm + orow;  // local t of pack start (+am*16)
  #pragma unroll
  for (int bn = 0; bn < 4; ++bn) {
    int   col  = n0 + wn + bn * 16 + lr;
    float bcol = bias[col];
    size_t tbase = ((size_t)bT * D_MODEL + col) * SEQ;
    #pragma unroll
    for (int am = 0; am < 4; ++am) {
      short4v pk;
      #pragma unroll
      for (int i = 0; i < 4; ++i) {
        float v = acc[am][bn][i] + bcol;
        unsigned short hv = f2bf(v);
        mixed[(size_t)(m0 + wm + am * 16 + orow + i) * D_MODEL + col] = hv;
        pk[i] = (short)hv;
      }
      if (WRITE_T)
        *(short4v*)&mixedT[tbase + tl0 + am * 16] = pk;
    }
  }
}

// ---------------------------------------------------------------------------
// Fused attention.  PRE_T: V^T staged from precomputed mixedT (coalesced);
// fallback: in-kernel scalar transpose scatter.
// ---------------------------------------------------------------------------
template<bool PRE_T>
__global__ __launch_bounds__(256, 4) void attn_kernel(
    const unsigned short* __restrict__ mixed,
    const unsigned short* __restrict__ mixedT,
    const float* __restrict__ mask, float* __restrict__ out)
{
  __shared__ unsigned short QP[QB * DHEAD];   // Q tile; later per-wave P stripes
  __shared__ unsigned short Xs[64 * DHEAD];   // K rows
  __shared__ unsigned short XTs[DHEAD * 64];  // V^T rows

  const int tid = threadIdx.x;
  const int l   = tid & 63;
  const int w   = tid >> 6;
  const int q0  = blockIdx.x * QB;
  const int h   = blockIdx.y;
  const int b   = blockIdx.z;
  const int lr  = l & 15;
  const int g   = l >> 4;
  const int lk  = g * 8;
  const size_t base  = ((size_t)b * SEQ) * D_MODEL + h * DHEAD;
  const size_t baseT = ((size_t)b * D_MODEL + h * DHEAD) * SEQ;

  const int srow = tid >> 3;          // 0..31 (+32 second pass)
  const int scol = (tid & 7) * 8;

  // ---- stage Q (64x64) ----
  #pragma unroll
  for (int rr = 0; rr < 2; ++rr) {
    int row = srow + rr * 32;
    bf16x8 v = *(const bf16x8*)&mixed[base + (size_t)(q0 + row) * D_MODEL + scol];
    *(bf16x8*)&QP[lswz(row, scol)] = v;
  }

  // ---- prefetch tile 0 ----
  bf16x8 xr[2], xtr[2];
  #pragma unroll
  for (int rr = 0; rr < 2; ++rr) {
    int row = srow + rr * 32;
    xr[rr] = *(const bf16x8*)&mixed[base + (size_t)row * D_MODEL + scol];
    if (PRE_T)
      xtr[rr] = *(const bf16x8*)&mixedT[baseT + (size_t)row * SEQ + scol];
  }

  __syncthreads();
  bf16x8 qf[2];
  qf[0] = *(const bf16x8*)&QP[lswz(w * 16 + lr, lk)];
  qf[1] = *(const bf16x8*)&QP[lswz(w * 16 + lr, 32 + lk)];
  // After this, QP rows [w*16, w*16+16) are wave-private P storage.

  float m_i[4], l_i[4];
  f32x4 cacc[4] = {};
  #pragma unroll
  for (int i = 0; i < 4; ++i) { m_i[i] = -1e30f; l_i[i] = 0.f; }

  const float SCL = 0.125f * LOG2E;

  for (int t0 = 0; t0 < SEQ; t0 += 64) {
    // ---- write prefetched regs -> LDS ----
    #pragma unroll
    for (int rr = 0; rr < 2; ++rr) {
      int row = srow + rr * 32;
      *(bf16x8*)&Xs[lswz(row, scol)] = xr[rr];
      if (PRE_T) {
        *(bf16x8*)&XTs[lswz(row, scol)] = xtr[rr];
      } else {
        #pragma unroll
        for (int j = 0; j < 8; ++j)
          XTs[lswz(scol + j, row)] = (unsigned short)xr[rr][j];
      }
    }
    __syncthreads();

    // ---- issue next tile's prefetch (consumed next iteration) ----
    if (t0 + 64 < SEQ) {
      #pragma unroll
      for (int rr = 0; rr < 2; ++rr) {
        int row = srow + rr * 32;
        xr[rr] = *(const bf16x8*)&mixed[base + (size_t)(t0 + 64 + row) * D_MODEL + scol];
        if (PRE_T)
          xtr[rr] = *(const bf16x8*)&mixedT[baseT + (size_t)row * SEQ + t0 + 64 + scol];
      }
    }

    float mk[4];
    #pragma unroll
    for (int nf = 0; nf < 4; ++nf)
      mk[nf] = mask[(size_t)b * SEQ + t0 + nf * 16 + lr] * LOG2E;

    // ---- S = Q @ K^T ----
    f32x4 sacc[4] = {};
    #pragma unroll
    for (int kf = 0; kf < 2; ++kf)
      #pragma unroll
      for (int nf = 0; nf < 4; ++nf) {
        bf16x8 kfr = *(const bf16x8*)&Xs[lswz(nf * 16 + lr, kf * 32 + lk)];
        sacc[nf] = __builtin_amdgcn_mfma_f32_16x16x32_bf16(
            qf[kf], kfr, sacc[nf], 0, 0, 0);
      }

    // ---- scale + mask (exp2 domain), online softmax ----
    #pragma unroll
    for (int nf = 0; nf < 4; ++nf)
      #pragma unroll
      for (int i = 0; i < 4; ++i)
        sacc[nf][i] = sacc[nf][i] * SCL + mk[nf];

    #pragma unroll
    for (int i = 0; i < 4; ++i) {
      float rm = fmaxf(fmaxf(sacc[0][i], sacc[1][i]),
                       fmaxf(sacc[2][i], sacc[3][i]));
      rm = fmaxf(rm, __shfl_xor(rm, 1));
      rm = fmaxf(rm, __shfl_xor(rm, 2));
      rm = fmaxf(rm, __shfl_xor(rm, 4));
      rm = fmaxf(rm, __shfl_xor(rm, 8));
      float mn = fmaxf(m_i[i], rm);
      float al = fexp2(m_i[i] - mn);
      float rs = 0.f;
      #pragma unroll
      for (int nf = 0; nf < 4; ++nf) {
        float pv = fexp2(sacc[nf][i] - mn);
        sacc[nf][i] = pv;
        rs += pv;
      }
      rs += __shfl_xor(rs, 1);
      rs += __shfl_xor(rs, 2);
      rs += __shfl_xor(rs, 4);
      rs += __shfl_xor(rs, 8);
      l_i[i] = l_i[i] * al + rs;
      m_i[i] = mn;
      #pragma unroll
      for (int nf = 0; nf < 4; ++nf) cacc[nf][i] *= al;
    }

    // ---- P -> own QP stripe (wave-private, no barrier) ----
    #pragma unroll
    for (int nf = 0; nf < 4; ++nf)
      #pragma unroll
      for (int i = 0; i < 4; ++i)
        QP[lswz(w * 16 + g * 4 + i, nf * 16 + lr)] = f2bf(sacc[nf][i]);

    // ---- ctx += P @ V ----
    bf16x8 pa[2];
    pa[0] = *(const bf16x8*)&QP[lswz(w * 16 + lr, lk)];
    pa[1] = *(const bf16x8*)&QP[lswz(w * 16 + lr, 32 + lk)];
    #pragma unroll
    for (int kf = 0; kf < 2; ++kf)
      #pragma unroll
      for (int nf = 0; nf < 4; ++nf) {
        bf16x8 vf = *(const bf16x8*)&XTs[lswz(nf * 16 + lr, kf * 32 + lk)];
        cacc[nf] = __builtin_amdgcn_mfma_f32_16x16x32_bf16(
            pa[kf], vf, cacc[nf], 0, 0, 0);
      }
    __syncthreads();  // Xs/XTs reads done before next iter's writes
  }

  // ---- normalize + store ----
  #pragma unroll
  for (int i = 0; i < 4; ++i) {
    float inv = __builtin_amdgcn_rcpf(l_i[i]);
    #pragma unroll
    for (int nf = 0; nf < 4; ++nf) {
      int row = q0 + w * 16 + g * 4 + i;
      int col = h * DHEAD + nf * 16 + lr;
      out[((size_t)b * SEQ + row) * D_MODEL + col] = cacc[nf][i] * inv;
    }
  }
}

// ---------------------------------------------------------------------------
extern "C" void kernel_launch(void* const* d_in, const int* in_sizes, int n_in,
                              void* d_out, int out_size, void* d_ws, size_t ws_size,
                              hipStream_t stream) {
  const float* x    = (const float*)d_in[0];
  const float* mask = (const float*)d_in[1];
  const float* W    = (const float*)d_in[2];
  const float* bias = (const float*)d_in[3];
  float* out        = (float*)d_out;

  unsigned short* mixed  = (unsigned short*)d_ws;          // 12.58 MB
  unsigned short* mixedT = mixed + (size_t)8192 * D_MODEL; // 12.58 MB
  const size_t need = (size_t)8192 * D_MODEL * 2 * 2;      // both buffers
  const bool preT = ws_size >= need;

  dim3 gp(8192 / 128, D_MODEL / 128);             // (64, 6)
  dim3 ga(SEQ / QB, NHEAD, BATCH);                // (16, 12, 8)

  if (preT) {
    proj_kernel<true><<<gp, 256, 0, stream>>>(x, W, bias, mixed, mixedT);
    attn_kernel<true><<<ga, 256, 0, stream>>>(mixed, mixedT, mask, out);
  } else {
    proj_kernel<false><<<gp, 256, 0, stream>>>(x, W, bias, mixed, mixed);
    attn_kernel<false><<<ga, 256, 0, stream>>>(mixed, mixed, mask, out);
  }
}